// Round 4
// baseline (790.022 us; speedup 1.0000x reference)
//
#include <hip/hip_runtime.h>

typedef unsigned long long u64;

// B = 64 == wavefront size; lane = batch index throughout.
// Groups of 64 destination nodes; ngroups = ceil(N/64) (<= 511 assumed).
// Pipeline: prep    (x -> xT[N,64] transpose; zero group counters)
//           hist    (per-block LDS histogram of 313 group counters)
//           scan    (1 block: group counts -> goff[ngroups+1], gcur)
//           scatter (bucket sort into groups; LDS-staged run-coalesced flush)
//           reduce  (1 block/group: LDS fp32-atomic accumulator, fused epilogue)

__global__ void prep_kernel(const float* __restrict__ x, float* __restrict__ xT,
                            int* __restrict__ gcnt, int N, int ngroups) {
    __shared__ float tile[64][65];
    int n0 = blockIdx.x * 64;
    int tid = threadIdx.x;
    for (int lin = tid; lin < 64 * 64; lin += 256) {
        int nl = lin & 63, b = lin >> 6;
        int n = n0 + nl;
        tile[b][nl] = (n < N) ? x[(long)b * N + n] : 0.f;
    }
    __syncthreads();
    for (int lin = tid; lin < 64 * 64; lin += 256) {
        int b = lin & 63, nl = lin >> 6;
        int n = n0 + nl;
        if (n < N) xT[(long)n * 64 + b] = tile[b][nl];
    }
    if (blockIdx.x == 0) {
        for (int i = tid; i <= ngroups; i += 256) gcnt[i] = 0;
    }
}

__global__ __launch_bounds__(256) void hist_kernel(const int* __restrict__ dst,
                                                   int* __restrict__ gcnt,
                                                   int E4, int ngroups) {
    __shared__ int h[512];
    int tid = threadIdx.x;
    for (int i = tid; i < ngroups; i += 256) h[i] = 0;
    __syncthreads();
    int base = blockIdx.x * 512;
#pragma unroll
    for (int k = 0; k < 2; ++k) {
        int i4 = base + k * 256 + tid;
        if (i4 < E4) {
            int4 d = ((const int4*)dst)[i4];
            atomicAdd(&h[d.x >> 6], 1);
            atomicAdd(&h[d.y >> 6], 1);
            atomicAdd(&h[d.z >> 6], 1);
            atomicAdd(&h[d.w >> 6], 1);
        }
    }
    __syncthreads();
    for (int i = tid; i < ngroups; i += 256) {
        if (h[i]) atomicAdd(&gcnt[i], h[i]);
    }
}

__global__ __launch_bounds__(512) void scan_kernel(const int* __restrict__ gcnt,
                                                   int* __restrict__ goff,
                                                   int* __restrict__ gcur,
                                                   int ngroups, int E) {
    __shared__ int sm[512];
    int t = threadIdx.x;
    int c = (t < ngroups) ? gcnt[t] : 0;
    sm[t] = c;
    __syncthreads();
    for (int d = 1; d < 512; d <<= 1) {
        int v = sm[t];
        if (t >= d) v += sm[t - d];
        __syncthreads();
        sm[t] = v;
        __syncthreads();
    }
    if (t < ngroups) {
        int ex = sm[t] - c;
        goff[t] = ex;
        gcur[t] = ex;
    }
    if (t == ngroups) goff[t] = E;  // == inclusive total
}

#define TILE 4096  // 512 threads * 8 edges

__global__ __launch_bounds__(512) void scatter_kernel(
        const float* __restrict__ adj, const float* __restrict__ w,
        const int* __restrict__ src, const int* __restrict__ dst,
        int* __restrict__ gcur, u64* __restrict__ packed, int E, int ngroups) {
    __shared__ int cnt[512];            // per-bucket count (dummy = ngroups)
    __shared__ int ofs[512];            // exclusive in-block offsets
    __shared__ int gbase[512];          // global base per bucket
    __shared__ int sm[512];
    __shared__ u64 staged[TILE];
    __shared__ unsigned short gof[TILE];

    int t = threadIdx.x;
    int base = blockIdx.x * TILE;
    for (int i = t; i <= ngroups; i += 512) cnt[i] = 0;
    __syncthreads();

    u64 pk[8]; int gk[8]; int rk[8];
#pragma unroll
    for (int k = 0; k < 8; ++k) {
        int e = base + k * 512 + t;
        int g; u64 p;
        if (e < E) {
            int d = dst[e];
            float c = adj[e] * w[e];
            g = d >> 6;
            p = ((u64)__float_as_uint(c) << 32)
              | (u64)(((unsigned int)src[e] << 6) | (unsigned int)(d & 63));
        } else {
            g = ngroups; p = 0;
        }
        pk[k] = p; gk[k] = g;
        rk[k] = atomicAdd(&cnt[g], 1);
    }
    __syncthreads();

    // in-block exclusive scan of cnt over ngroups+1 buckets (padded to 512)
    int c = (t <= ngroups) ? cnt[t] : 0;
    sm[t] = c;
    __syncthreads();
    for (int d = 1; d < 512; d <<= 1) {
        int v = sm[t];
        if (t >= d) v += sm[t - d];
        __syncthreads();
        sm[t] = v;
        __syncthreads();
    }
    ofs[t] = sm[t] - c;
    if (t < ngroups && c > 0) gbase[t] = atomicAdd(&gcur[t], c);
    __syncthreads();

    // stage records ordered by bucket
#pragma unroll
    for (int k = 0; k < 8; ++k) {
        int pos = ofs[gk[k]] + rk[k];
        staged[pos] = pk[k];
        gof[pos] = (unsigned short)gk[k];
    }
    __syncthreads();

    // flush: consecutive i within a bucket-run -> consecutive global dest
#pragma unroll
    for (int k = 0; k < 8; ++k) {
        int i = k * 512 + t;
        int g = gof[i];
        if (g < ngroups) packed[gbase[g] + (i - ofs[g])] = staged[i];
    }
}

__global__ __launch_bounds__(512) void reduce_kernel(
        const int* __restrict__ goff, const u64* __restrict__ packed,
        const float* __restrict__ xT, const float* __restrict__ x,
        const float* __restrict__ self_w, const float* __restrict__ bias,
        float* __restrict__ out, int N) {
    __shared__ float acc[64 * 65];      // [dstLocal][b], pitch 65: 2-way banks, free
    int tid = threadIdx.x;
    int wave = tid >> 6;                // 0..7
    int lane = tid & 63;                // batch index
    int g = blockIdx.x;
    for (int i = tid; i < 64 * 65; i += 512) acc[i] = 0.f;
    __syncthreads();

    int s = __builtin_amdgcn_readfirstlane(goff[g]);
    int e = __builtin_amdgcn_readfirstlane(goff[g + 1]);
    int per = (e - s + 7) >> 3;
    int j0 = s + wave * per;
    int j1 = min(e, j0 + per);

    int j = j0;
    for (; j + 4 <= j1; j += 4) {
        u64 p0 = packed[j], p1 = packed[j + 1], p2 = packed[j + 2], p3 = packed[j + 3];
        unsigned int l0 = (unsigned int)p0, l1 = (unsigned int)p1;
        unsigned int l2 = (unsigned int)p2, l3 = (unsigned int)p3;
        float v0 = __uint_as_float((unsigned int)(p0 >> 32)) * xT[(l0 >> 6) * 64 + lane];
        float v1 = __uint_as_float((unsigned int)(p1 >> 32)) * xT[(l1 >> 6) * 64 + lane];
        float v2 = __uint_as_float((unsigned int)(p2 >> 32)) * xT[(l2 >> 6) * 64 + lane];
        float v3 = __uint_as_float((unsigned int)(p3 >> 32)) * xT[(l3 >> 6) * 64 + lane];
        atomicAdd(&acc[(l0 & 63) * 65 + lane], v0);
        atomicAdd(&acc[(l1 & 63) * 65 + lane], v1);
        atomicAdd(&acc[(l2 & 63) * 65 + lane], v2);
        atomicAdd(&acc[(l3 & 63) * 65 + lane], v3);
    }
    for (; j < j1; ++j) {
        u64 p = packed[j];
        unsigned int lo = (unsigned int)p;
        float v = __uint_as_float((unsigned int)(p >> 32)) * xT[(lo >> 6) * 64 + lane];
        atomicAdd(&acc[(lo & 63) * 65 + lane], v);
    }
    __syncthreads();

    // epilogue: n = n0 + lane; each wave writes 8 batch rows, 256B coalesced
    int n = g * 64 + lane;
    float sl = 0.f, bi = 0.f;
    if (n < N) { sl = x[n] * self_w[n]; bi = bias[n]; }  // x row 0 (ref quirk)
#pragma unroll
    for (int i = 0; i < 8; ++i) {
        int b = wave * 8 + i;
        if (n < N) {
            float v = acc[lane * 65 + b] * sl + bi;      // (lane+b)%32: 2-way, free
            out[(long)b * N + n] = fmaxf(v, 0.f);
        }
    }
}

extern "C" void kernel_launch(void* const* d_in, const int* in_sizes, int n_in,
                              void* d_out, int out_size, void* d_ws, size_t ws_size,
                              hipStream_t stream) {
    const float* x      = (const float*)d_in[0];
    const float* adj    = (const float*)d_in[1];
    const float* w      = (const float*)d_in[2];
    const float* self_w = (const float*)d_in[3];
    const float* bias   = (const float*)d_in[4];
    const int*   src    = (const int*)d_in[5];
    const int*   dst    = (const int*)d_in[6];

    int N = in_sizes[3];            // 20000
    int E = in_sizes[1];            // 1,280,000
    (void)n_in; (void)ws_size; (void)out_size;

    int ngroups = (N + 63) / 64;    // 313 (must be <= 511)

    // workspace layout: packed first (8B-aligned at base), then 4B arrays
    u64*   packed = (u64*)d_ws;                       // E
    float* xT     = (float*)(packed + E);             // N*64
    int*   gcnt   = (int*)(xT + (size_t)N * 64);      // ngroups+1
    int*   goff   = gcnt + 512;                       // ngroups+1
    int*   gcur   = goff + 512;                       // ngroups
    float* out    = (float*)d_out;

    int E4 = E / 4;

    hipLaunchKernelGGL(prep_kernel, dim3(ngroups), dim3(256), 0, stream,
                       x, xT, gcnt, N, ngroups);
    hipLaunchKernelGGL(hist_kernel, dim3((E4 + 511) / 512), dim3(256), 0, stream,
                       dst, gcnt, E4, ngroups);
    hipLaunchKernelGGL(scan_kernel, dim3(1), dim3(512), 0, stream,
                       gcnt, goff, gcur, ngroups, E);
    hipLaunchKernelGGL(scatter_kernel, dim3((E + TILE - 1) / TILE), dim3(512), 0, stream,
                       adj, w, src, dst, gcur, packed, E, ngroups);
    hipLaunchKernelGGL(reduce_kernel, dim3(ngroups), dim3(512), 0, stream,
                       goff, packed, xT, x, self_w, bias, out, N);
}